// Round 1
// baseline (175.917 us; speedup 1.0000x reference)
//
#include <hip/hip_runtime.h>

typedef short short8 __attribute__((ext_vector_type(8)));
typedef float floatx4 __attribute__((ext_vector_type(4)));
typedef __attribute__((address_space(1))) const void gvoid;
typedef __attribute__((address_space(3))) void svoid;

#define SCALE_POS 2.0f
#define SCALE_NEG 40.0f
#define THRESH 0.5f
#define MARGIN 0.1f
#define EPSV 1e-5f

__device__ __forceinline__ unsigned short f2bf(float f) {
    unsigned u = __float_as_uint(f);
    u += 0x7fffu + ((u >> 16) & 1u);   // round-to-nearest-even
    return (unsigned short)(u >> 16);
}
// order-preserving float<->uint map (no NaNs present)
__device__ __forceinline__ unsigned f2ord(float f) {
    unsigned u = __float_as_uint(f);
    return (u & 0x80000000u) ? ~u : (u | 0x80000000u);
}
__device__ __forceinline__ float ord2f(unsigned e) {
    unsigned v = (e & 0x80000000u) ? (e & 0x7fffffffu) : ~e;
    return __uint_as_float(v);
}

#define ORD_POS_INF 0xff800000u   // f2ord(+inf)
#define ORD_NEG_INF 0x007fffffu   // f2ord(-inf)

// ---- kernel 1: fp32 -> bf16 cast + stat init ----
__global__ void k_init(const float* __restrict__ feats,
                       unsigned short* __restrict__ fb16,
                       unsigned* __restrict__ minp, unsigned* __restrict__ maxn,
                       float* __restrict__ psum, float* __restrict__ nsum,
                       int total4, int B) {
    int i = blockIdx.x * blockDim.x + threadIdx.x;
    if (i < total4) {
        float4 v = ((const float4*)feats)[i];
        ushort4 o;
        o.x = f2bf(v.x); o.y = f2bf(v.y); o.z = f2bf(v.z); o.w = f2bf(v.w);
        ((ushort4*)fb16)[i] = o;
    }
    if (i < B) {
        minp[i] = ORD_POS_INF;
        maxn[i] = ORD_NEG_INF;
        psum[i] = 0.f;
        nsum[i] = 0.f;
    }
}

// ---- kernels 2/3: fused GEMM + row-stat epilogues ----
// 128x128 block tile, 256 threads = 4 waves in 2x2, each wave 64x64 via
// 4x4 grid of mfma_f32_16x16x32_bf16. B-operand is feats itself (B^T form).
template <int PASS>
__global__ void k_gemm(const unsigned short* __restrict__ fb16,
                       const int* __restrict__ labels,
                       unsigned* __restrict__ minp_ord,
                       unsigned* __restrict__ maxn_ord,
                       float* __restrict__ psum,
                       float* __restrict__ nsum,
                       int D) {
    __shared__ __align__(16) unsigned short As[128 * 32];  // 8 KB
    __shared__ __align__(16) unsigned short Bs[128 * 32];  // 8 KB
    __shared__ int labR[128], labC[128];
    __shared__ float mpS[128], mnS[128];

    const int tid = threadIdx.x;
    const int lane = tid & 63;
    const int wave = tid >> 6;
    const int wr = wave >> 1, wc = wave & 1;
    const int rowBase = blockIdx.y * 128;
    const int colBase = blockIdx.x * 128;

    if (tid < 128) {
        labR[tid] = labels[rowBase + tid];
        if (PASS == 2) {
            mpS[tid] = ord2f(minp_ord[rowBase + tid]);
            mnS[tid] = ord2f(maxn_ord[rowBase + tid]);
        }
    } else {
        labC[tid - 128] = labels[colBase + tid - 128];
    }

    // --- staging: 8 chunks of 1KB per tile; wave handles chunks 2w,2w+1 ---
    const int c0 = wave * 2, c1 = wave * 2 + 1;
    const int srow = lane >> 2;        // row within 16-row chunk
    const int scol = (lane & 3) * 8;   // ushort col offset (16B per lane)
    const unsigned short* gA0 = fb16 + (size_t)(rowBase + c0 * 16 + srow) * D + scol;
    const unsigned short* gA1 = fb16 + (size_t)(rowBase + c1 * 16 + srow) * D + scol;
    const unsigned short* gB0 = fb16 + (size_t)(colBase + c0 * 16 + srow) * D + scol;
    const unsigned short* gB1 = fb16 + (size_t)(colBase + c1 * 16 + srow) * D + scol;
    unsigned short* lA0 = As + c0 * 512 + lane * 8;   // LDS = chunk base + lane*16B
    unsigned short* lA1 = As + c1 * 512 + lane * 8;
    unsigned short* lB0 = Bs + c0 * 512 + lane * 8;
    unsigned short* lB1 = Bs + c1 * 512 + lane * 8;

    // --- fragment read offsets (A-layout: row=lane&15, k=quad*8.. ) ---
    const int q = lane >> 4;
    const int cIn = lane & 15;
    int aOff[4], bOff[4];
#pragma unroll
    for (int i = 0; i < 4; ++i) {
        aOff[i] = (wr * 64 + i * 16 + cIn) * 32 + q * 8;
        bOff[i] = (wc * 64 + i * 16 + cIn) * 32 + q * 8;
    }

    floatx4 acc[4][4] = {};

    const int KT = D >> 5;
    for (int kt = 0; kt < KT; ++kt) {
        const int kOff = kt * 32;
        __syncthreads();  // previous iter's LDS reads done
        __builtin_amdgcn_global_load_lds((gvoid*)(gA0 + kOff), (svoid*)lA0, 16, 0, 0);
        __builtin_amdgcn_global_load_lds((gvoid*)(gA1 + kOff), (svoid*)lA1, 16, 0, 0);
        __builtin_amdgcn_global_load_lds((gvoid*)(gB0 + kOff), (svoid*)lB0, 16, 0, 0);
        __builtin_amdgcn_global_load_lds((gvoid*)(gB1 + kOff), (svoid*)lB1, 16, 0, 0);
        __syncthreads();  // drains vmcnt before barrier -> tiles ready

        short8 a[4], b[4];
#pragma unroll
        for (int i = 0; i < 4; ++i) a[i] = *(const short8*)(As + aOff[i]);
#pragma unroll
        for (int i = 0; i < 4; ++i) b[i] = *(const short8*)(Bs + bOff[i]);
#pragma unroll
        for (int i = 0; i < 4; ++i)
#pragma unroll
            for (int j = 0; j < 4; ++j)
                acc[i][j] = __builtin_amdgcn_mfma_f32_16x16x32_bf16(a[i], b[j], acc[i][j], 0, 0, 0);
    }

    // --- epilogue: C/D layout col=lane&15, row=quad*4+reg ---
#pragma unroll
    for (int mi = 0; mi < 4; ++mi) {
#pragma unroll
        for (int r = 0; r < 4; ++r) {
            const int rLoc = wr * 64 + mi * 16 + q * 4 + r;
            const int rLab = labR[rLoc];
            if (PASS == 1) {
                float vmin = 1e30f, vmax = -1e30f;
#pragma unroll
                for (int ni = 0; ni < 4; ++ni) {
                    float s = acc[mi][ni][r];
                    int cLab = labC[wc * 64 + ni * 16 + cIn];
                    if (rLab == cLab) {
                        if (s < 1.0f - EPSV) vmin = fminf(vmin, s);
                    } else {
                        vmax = fmaxf(vmax, s);
                    }
                }
#pragma unroll
                for (int off = 8; off; off >>= 1) {
                    vmin = fminf(vmin, __shfl_xor(vmin, off, 16));
                    vmax = fmaxf(vmax, __shfl_xor(vmax, off, 16));
                }
                if (cIn == 0) {
                    if (vmin < 1e30f) atomicMin(&minp_ord[rowBase + rLoc], f2ord(vmin));
                    if (vmax > -1e30f) atomicMax(&maxn_ord[rowBase + rLoc], f2ord(vmax));
                }
            } else {
                const float mp = mpS[rLoc] - MARGIN;  // neg kept if s > mp
                const float mn = mnS[rLoc] + MARGIN;  // pos kept if s < mn
                float ps = 0.f, ns = 0.f;
#pragma unroll
                for (int ni = 0; ni < 4; ++ni) {
                    float s = acc[mi][ni][r];
                    int cLab = labC[wc * 64 + ni * 16 + cIn];
                    if (rLab == cLab) {
                        if (s < 1.0f - EPSV && s < mn) ps += expf(-SCALE_POS * (s - THRESH));
                    } else {
                        if (s > mp) ns += expf(SCALE_NEG * (s - THRESH));
                    }
                }
#pragma unroll
                for (int off = 8; off; off >>= 1) {
                    ps += __shfl_xor(ps, off, 16);
                    ns += __shfl_xor(ns, off, 16);
                }
                if (cIn == 0) {
                    if (ps != 0.f) atomicAdd(&psum[rowBase + rLoc], ps);
                    if (ns != 0.f) atomicAdd(&nsum[rowBase + rLoc], ns);
                }
            }
        }
    }
}

// ---- kernel 4: final scalar reduction ----
__global__ void k_final(const float* __restrict__ psum, const float* __restrict__ nsum,
                        float* __restrict__ out, int B) {
    __shared__ float red[4];
    float acc = 0.f;
    for (int i = threadIdx.x; i < B; i += 256) {
        float p = psum[i], n = nsum[i];
        if (p > 0.f && n > 0.f)
            acc += log1pf(p) * (1.0f / SCALE_POS) + log1pf(n) * (1.0f / SCALE_NEG);
    }
#pragma unroll
    for (int off = 32; off; off >>= 1) acc += __shfl_down(acc, off, 64);
    if ((threadIdx.x & 63) == 0) red[threadIdx.x >> 6] = acc;
    __syncthreads();
    if (threadIdx.x == 0) out[0] = (red[0] + red[1] + red[2] + red[3]) / (float)B;
}

extern "C" void kernel_launch(void* const* d_in, const int* in_sizes, int n_in,
                              void* d_out, int out_size, void* d_ws, size_t ws_size,
                              hipStream_t stream) {
    const float* feats = (const float*)d_in[0];
    const int* labels = (const int*)d_in[1];
    const int B = in_sizes[1];            // 4096
    const int D = in_sizes[0] / B;        // 1024

    char* ws = (char*)d_ws;
    unsigned short* fb16 = (unsigned short*)ws;
    size_t off = (size_t)B * D * sizeof(unsigned short);
    unsigned* minp = (unsigned*)(ws + off); off += (size_t)B * 4;
    unsigned* maxn = (unsigned*)(ws + off); off += (size_t)B * 4;
    float* psum = (float*)(ws + off); off += (size_t)B * 4;
    float* nsum = (float*)(ws + off); off += (size_t)B * 4;

    const int total4 = B * D / 4;
    k_init<<<(total4 + 255) / 256, 256, 0, stream>>>(feats, fb16, minp, maxn, psum, nsum, total4, B);

    dim3 grid(B / 128, B / 128);
    k_gemm<1><<<grid, 256, 0, stream>>>(fb16, labels, minp, maxn, psum, nsum, D);
    k_gemm<2><<<grid, 256, 0, stream>>>(fb16, labels, minp, maxn, psum, nsum, D);

    k_final<<<1, 256, 0, stream>>>(psum, nsum, (float*)d_out, B);
}

// Round 2
// 165.605 us; speedup vs baseline: 1.0623x; 1.0623x over previous
//
#include <hip/hip_runtime.h>

typedef short short8 __attribute__((ext_vector_type(8)));
typedef _Float16 half8 __attribute__((ext_vector_type(8)));
typedef float floatx4 __attribute__((ext_vector_type(4)));
typedef __attribute__((address_space(1))) const void gvoid;
typedef __attribute__((address_space(3))) void svoid;

#define SCALE_POS 2.0f
#define SCALE_NEG 40.0f
#define THRESH 0.5f
#define MARGIN 0.1f
#define EPSV 1e-5f

__device__ __forceinline__ unsigned short f2bf(float f) {
    unsigned u = __float_as_uint(f);
    u += 0x7fffu + ((u >> 16) & 1u);   // round-to-nearest-even
    return (unsigned short)(u >> 16);
}
// order-preserving float<->uint map (no NaNs present)
__device__ __forceinline__ unsigned f2ord(float f) {
    unsigned u = __float_as_uint(f);
    return (u & 0x80000000u) ? ~u : (u | 0x80000000u);
}
__device__ __forceinline__ float ord2f(unsigned e) {
    unsigned v = (e & 0x80000000u) ? (e & 0x7fffffffu) : ~e;
    return __uint_as_float(v);
}

#define ORD_POS_INF 0xff800000u   // f2ord(+inf)
#define ORD_NEG_INF 0x007fffffu   // f2ord(-inf)

// ---- kernel 1: fp32 -> bf16 cast + stat init ----
__global__ void k_init(const float* __restrict__ feats,
                       unsigned short* __restrict__ fb16,
                       unsigned* __restrict__ minp, unsigned* __restrict__ maxn,
                       float* __restrict__ psum, float* __restrict__ nsum,
                       int total4, int B) {
    int i = blockIdx.x * blockDim.x + threadIdx.x;
    if (i < total4) {
        float4 v = ((const float4*)feats)[i];
        ushort4 o;
        o.x = f2bf(v.x); o.y = f2bf(v.y); o.z = f2bf(v.z); o.w = f2bf(v.w);
        ((ushort4*)fb16)[i] = o;
    }
    if (i < B) {
        minp[i] = ORD_POS_INF;
        maxn[i] = ORD_NEG_INF;
        psum[i] = 0.f;
        nsum[i] = 0.f;
    }
}

// =====================================================================
// SYMMETRIC PATH
// Pass 1: GEMM over upper-triangular 128x128 block tiles (rb <= cb).
// Epilogue computes min_pos/max_neg for BOTH row-block rows (reduce over
// columns) and col-block rows (reduce over rows, via symmetry), and stores
// the tile as packed fp16 (per-thread 64 contiguous halves) to ws.
// =====================================================================
__global__ void k_gemm_sym(const unsigned short* __restrict__ fb16,
                           const int* __restrict__ labels,
                           unsigned* __restrict__ minp_ord,
                           unsigned* __restrict__ maxn_ord,
                           _Float16* __restrict__ simh,
                           int D, int nb) {
    __shared__ __align__(16) unsigned short As[128 * 32];  // 8 KB
    __shared__ __align__(16) unsigned short Bs[128 * 32];  // 8 KB
    __shared__ int labR[128], labC[128];

    // decode upper-tri block index -> (rb, cb), rb <= cb
    int t = blockIdx.x;
    int rb = 0, rem = t;
    while (rem >= nb - rb) { rem -= nb - rb; ++rb; }
    const int cb = rb + rem;

    const int tid = threadIdx.x;
    const int lane = tid & 63;
    const int wave = tid >> 6;
    const int wr = wave >> 1, wc = wave & 1;
    const int rowBase = rb * 128;
    const int colBase = cb * 128;

    if (tid < 128) labR[tid] = labels[rowBase + tid];
    else           labC[tid - 128] = labels[colBase + tid - 128];

    // --- staging: 8 chunks of 1KB per tile; wave handles chunks 2w,2w+1 ---
    const int c0 = wave * 2, c1 = wave * 2 + 1;
    const int srow = lane >> 2;
    const int scol = (lane & 3) * 8;
    const unsigned short* gA0 = fb16 + (size_t)(rowBase + c0 * 16 + srow) * D + scol;
    const unsigned short* gA1 = fb16 + (size_t)(rowBase + c1 * 16 + srow) * D + scol;
    const unsigned short* gB0 = fb16 + (size_t)(colBase + c0 * 16 + srow) * D + scol;
    const unsigned short* gB1 = fb16 + (size_t)(colBase + c1 * 16 + srow) * D + scol;
    unsigned short* lA0 = As + c0 * 512 + lane * 8;
    unsigned short* lA1 = As + c1 * 512 + lane * 8;
    unsigned short* lB0 = Bs + c0 * 512 + lane * 8;
    unsigned short* lB1 = Bs + c1 * 512 + lane * 8;

    const int q = lane >> 4;
    const int cIn = lane & 15;
    int aOff[4], bOff[4];
#pragma unroll
    for (int i = 0; i < 4; ++i) {
        aOff[i] = (wr * 64 + i * 16 + cIn) * 32 + q * 8;
        bOff[i] = (wc * 64 + i * 16 + cIn) * 32 + q * 8;
    }

    floatx4 acc[4][4] = {};

    const int KT = D >> 5;
    for (int kt = 0; kt < KT; ++kt) {
        const int kOff = kt * 32;
        __syncthreads();
        __builtin_amdgcn_global_load_lds((gvoid*)(gA0 + kOff), (svoid*)lA0, 16, 0, 0);
        __builtin_amdgcn_global_load_lds((gvoid*)(gA1 + kOff), (svoid*)lA1, 16, 0, 0);
        __builtin_amdgcn_global_load_lds((gvoid*)(gB0 + kOff), (svoid*)lB0, 16, 0, 0);
        __builtin_amdgcn_global_load_lds((gvoid*)(gB1 + kOff), (svoid*)lB1, 16, 0, 0);
        __syncthreads();

        short8 a[4], b[4];
#pragma unroll
        for (int i = 0; i < 4; ++i) a[i] = *(const short8*)(As + aOff[i]);
#pragma unroll
        for (int i = 0; i < 4; ++i) b[i] = *(const short8*)(Bs + bOff[i]);
#pragma unroll
        for (int i = 0; i < 4; ++i)
#pragma unroll
            for (int j = 0; j < 4; ++j)
                acc[i][j] = __builtin_amdgcn_mfma_f32_16x16x32_bf16(a[i], b[j], acc[i][j], 0, 0, 0);
    }

    // preload labels into regs (C/D layout: col=cIn, row=q*4+r within 16x16)
    int rLabv[16];
#pragma unroll
    for (int mi = 0; mi < 4; ++mi)
#pragma unroll
        for (int rr = 0; rr < 4; ++rr)
            rLabv[mi * 4 + rr] = labR[wr * 64 + mi * 16 + q * 4 + rr];
    int cLabv[4];
#pragma unroll
    for (int ni = 0; ni < 4; ++ni)
        cLabv[ni] = labC[wc * 64 + ni * 16 + cIn];

    // --- store tile as packed fp16: thread-major, 64 contiguous halves ---
    {
        half8* dst = (half8*)(simh + (size_t)t * 16384 + (size_t)tid * 64);
#pragma unroll
        for (int mi = 0; mi < 4; ++mi) {
            half8 h0, h1;
#pragma unroll
            for (int ni = 0; ni < 2; ++ni)
#pragma unroll
                for (int rr = 0; rr < 4; ++rr) {
                    h0[ni * 4 + rr] = (_Float16)acc[mi][ni][rr];
                    h1[ni * 4 + rr] = (_Float16)acc[mi][ni + 2][rr];
                }
            dst[mi * 2] = h0;
            dst[mi * 2 + 1] = h1;
        }
    }

    // --- row stats: reduce over columns (ni in-thread, cIn via shuffle) ---
#pragma unroll
    for (int mi = 0; mi < 4; ++mi) {
#pragma unroll
        for (int rr = 0; rr < 4; ++rr) {
            const int rLoc = wr * 64 + mi * 16 + q * 4 + rr;
            const int rLab = rLabv[mi * 4 + rr];
            float vmin = 1e30f, vmax = -1e30f;
#pragma unroll
            for (int ni = 0; ni < 4; ++ni) {
                float s = acc[mi][ni][rr];
                if (rLab == cLabv[ni]) {
                    if (s < 1.0f - EPSV) vmin = fminf(vmin, s);
                } else {
                    vmax = fmaxf(vmax, s);
                }
            }
#pragma unroll
            for (int off = 8; off; off >>= 1) {
                vmin = fminf(vmin, __shfl_xor(vmin, off, 16));
                vmax = fmaxf(vmax, __shfl_xor(vmax, off, 16));
            }
            if (cIn == 0) {
                if (vmin < 1e30f) atomicMin(&minp_ord[rowBase + rLoc], f2ord(vmin));
                if (vmax > -1e30f) atomicMax(&maxn_ord[rowBase + rLoc], f2ord(vmax));
            }
        }
    }

    // --- col stats via symmetry (off-diagonal blocks only) ---
    if (rb != cb) {
#pragma unroll
        for (int ni = 0; ni < 4; ++ni) {
            const int cLab = cLabv[ni];
            float vmin = 1e30f, vmax = -1e30f;
#pragma unroll
            for (int mi = 0; mi < 4; ++mi)
#pragma unroll
                for (int rr = 0; rr < 4; ++rr) {
                    float s = acc[mi][ni][rr];
                    if (rLabv[mi * 4 + rr] == cLab) {
                        if (s < 1.0f - EPSV) vmin = fminf(vmin, s);
                    } else {
                        vmax = fmaxf(vmax, s);
                    }
                }
            vmin = fminf(vmin, __shfl_xor(vmin, 16, 64));
            vmin = fminf(vmin, __shfl_xor(vmin, 32, 64));
            vmax = fmaxf(vmax, __shfl_xor(vmax, 16, 64));
            vmax = fmaxf(vmax, __shfl_xor(vmax, 32, 64));
            if (q == 0) {
                const int cLoc = wc * 64 + ni * 16 + cIn;
                if (vmin < 1e30f) atomicMin(&minp_ord[colBase + cLoc], f2ord(vmin));
                if (vmax > -1e30f) atomicMax(&maxn_ord[colBase + cLoc], f2ord(vmax));
            }
        }
    }
}

// =====================================================================
// Pass 2 (symmetric path): read packed fp16 tiles, gated exp sums for both
// row-direction and (off-diagonal) col-direction. One exp per element.
// =====================================================================
__global__ void k_sum2(const _Float16* __restrict__ simh,
                       const int* __restrict__ labels,
                       const unsigned* __restrict__ minp_ord,
                       const unsigned* __restrict__ maxn_ord,
                       float* __restrict__ psum, float* __restrict__ nsum,
                       int nb) {
    __shared__ int labR[128], labC[128];
    __shared__ float mpR[128], mnR[128], mpC[128], mnC[128];

    int t = blockIdx.x;
    int rb = 0, rem = t;
    while (rem >= nb - rb) { rem -= nb - rb; ++rb; }
    const int cb = rb + rem;

    const int tid = threadIdx.x;
    const int lane = tid & 63;
    const int wave = tid >> 6;
    const int wr = wave >> 1, wc = wave & 1;
    const int rowBase = rb * 128;
    const int colBase = cb * 128;
    const int q = lane >> 4;
    const int cIn = lane & 15;

    if (tid < 128) {
        labR[tid] = labels[rowBase + tid];
        mpR[tid] = ord2f(minp_ord[rowBase + tid]);
        mnR[tid] = ord2f(maxn_ord[rowBase + tid]);
    } else {
        int j = tid - 128;
        labC[j] = labels[colBase + j];
        mpC[j] = ord2f(minp_ord[colBase + j]);
        mnC[j] = ord2f(maxn_ord[colBase + j]);
    }
    __syncthreads();

    int rLabv[16];
    float mpRv[16], mnRv[16];
#pragma unroll
    for (int mi = 0; mi < 4; ++mi)
#pragma unroll
        for (int rr = 0; rr < 4; ++rr) {
            int rLoc = wr * 64 + mi * 16 + q * 4 + rr;
            rLabv[mi * 4 + rr] = labR[rLoc];
            mpRv[mi * 4 + rr] = mpR[rLoc] - MARGIN;   // neg kept if s > this
            mnRv[mi * 4 + rr] = mnR[rLoc] + MARGIN;   // pos kept if s < this
        }
    int cLabv[4];
    float mpCv[4], mnCv[4];
#pragma unroll
    for (int ni = 0; ni < 4; ++ni) {
        int cLoc = wc * 64 + ni * 16 + cIn;
        cLabv[ni] = labC[cLoc];
        mpCv[ni] = mpC[cLoc] - MARGIN;
        mnCv[ni] = mnC[cLoc] + MARGIN;
    }

    const half8* src = (const half8*)(simh + (size_t)t * 16384 + (size_t)tid * 64);
    half8 hv[8];
#pragma unroll
    for (int v = 0; v < 8; ++v) hv[v] = src[v];

    float rps[16] = {}, rns[16] = {};
    float cps[4] = {}, cns[4] = {};
    const bool offd = (rb != cb);

#pragma unroll
    for (int mi = 0; mi < 4; ++mi)
#pragma unroll
        for (int ni = 0; ni < 4; ++ni)
#pragma unroll
            for (int rr = 0; rr < 4; ++rr) {
                const int idx = mi * 16 + ni * 4 + rr;
                const float s = (float)hv[idx >> 3][idx & 7];
                const int ri = mi * 4 + rr;
                if (rLabv[ri] == cLabv[ni]) {
                    if (s < 1.0f - EPSV) {
                        float e = __expf(-SCALE_POS * (s - THRESH));
                        if (s < mnRv[ri]) rps[ri] += e;
                        if (offd && s < mnCv[ni]) cps[ni] += e;
                    }
                } else {
                    float e = __expf(SCALE_NEG * (s - THRESH));
                    if (s > mpRv[ri]) rns[ri] += e;
                    if (offd && s > mpCv[ni]) cns[ni] += e;
                }
            }

    // row reduction: shuffle over cIn (width 16)
#pragma unroll
    for (int i = 0; i < 16; ++i) {
#pragma unroll
        for (int off = 8; off; off >>= 1) {
            rps[i] += __shfl_xor(rps[i], off, 16);
            rns[i] += __shfl_xor(rns[i], off, 16);
        }
        if (cIn == 0) {
            const int rLoc = wr * 64 + (i >> 2) * 16 + q * 4 + (i & 3);
            if (rps[i] != 0.f) atomicAdd(&psum[rowBase + rLoc], rps[i]);
            if (rns[i] != 0.f) atomicAdd(&nsum[rowBase + rLoc], rns[i]);
        }
    }
    // col reduction: shuffle over q
    if (offd) {
#pragma unroll
        for (int ni = 0; ni < 4; ++ni) {
            cps[ni] += __shfl_xor(cps[ni], 16, 64);
            cps[ni] += __shfl_xor(cps[ni], 32, 64);
            cns[ni] += __shfl_xor(cns[ni], 16, 64);
            cns[ni] += __shfl_xor(cns[ni], 32, 64);
            if (q == 0) {
                const int cLoc = wc * 64 + ni * 16 + cIn;
                if (cps[ni] != 0.f) atomicAdd(&psum[colBase + cLoc], cps[ni]);
                if (cns[ni] != 0.f) atomicAdd(&nsum[colBase + cLoc], cns[ni]);
            }
        }
    }
}

// =====================================================================
// FALLBACK PATH (round-1): full-grid GEMM twice, no materialization
// =====================================================================
template <int PASS>
__global__ void k_gemm(const unsigned short* __restrict__ fb16,
                       const int* __restrict__ labels,
                       unsigned* __restrict__ minp_ord,
                       unsigned* __restrict__ maxn_ord,
                       float* __restrict__ psum,
                       float* __restrict__ nsum,
                       int D) {
    __shared__ __align__(16) unsigned short As[128 * 32];
    __shared__ __align__(16) unsigned short Bs[128 * 32];
    __shared__ int labR[128], labC[128];
    __shared__ float mpS[128], mnS[128];

    const int tid = threadIdx.x;
    const int lane = tid & 63;
    const int wave = tid >> 6;
    const int wr = wave >> 1, wc = wave & 1;
    const int rowBase = blockIdx.y * 128;
    const int colBase = blockIdx.x * 128;

    if (tid < 128) {
        labR[tid] = labels[rowBase + tid];
        if (PASS == 2) {
            mpS[tid] = ord2f(minp_ord[rowBase + tid]);
            mnS[tid] = ord2f(maxn_ord[rowBase + tid]);
        }
    } else {
        labC[tid - 128] = labels[colBase + tid - 128];
    }

    const int c0 = wave * 2, c1 = wave * 2 + 1;
    const int srow = lane >> 2;
    const int scol = (lane & 3) * 8;
    const unsigned short* gA0 = fb16 + (size_t)(rowBase + c0 * 16 + srow) * D + scol;
    const unsigned short* gA1 = fb16 + (size_t)(rowBase + c1 * 16 + srow) * D + scol;
    const unsigned short* gB0 = fb16 + (size_t)(colBase + c0 * 16 + srow) * D + scol;
    const unsigned short* gB1 = fb16 + (size_t)(colBase + c1 * 16 + srow) * D + scol;
    unsigned short* lA0 = As + c0 * 512 + lane * 8;
    unsigned short* lA1 = As + c1 * 512 + lane * 8;
    unsigned short* lB0 = Bs + c0 * 512 + lane * 8;
    unsigned short* lB1 = Bs + c1 * 512 + lane * 8;

    const int q = lane >> 4;
    const int cIn = lane & 15;
    int aOff[4], bOff[4];
#pragma unroll
    for (int i = 0; i < 4; ++i) {
        aOff[i] = (wr * 64 + i * 16 + cIn) * 32 + q * 8;
        bOff[i] = (wc * 64 + i * 16 + cIn) * 32 + q * 8;
    }

    floatx4 acc[4][4] = {};

    const int KT = D >> 5;
    for (int kt = 0; kt < KT; ++kt) {
        const int kOff = kt * 32;
        __syncthreads();
        __builtin_amdgcn_global_load_lds((gvoid*)(gA0 + kOff), (svoid*)lA0, 16, 0, 0);
        __builtin_amdgcn_global_load_lds((gvoid*)(gA1 + kOff), (svoid*)lA1, 16, 0, 0);
        __builtin_amdgcn_global_load_lds((gvoid*)(gB0 + kOff), (svoid*)lB0, 16, 0, 0);
        __builtin_amdgcn_global_load_lds((gvoid*)(gB1 + kOff), (svoid*)lB1, 16, 0, 0);
        __syncthreads();

        short8 a[4], b[4];
#pragma unroll
        for (int i = 0; i < 4; ++i) a[i] = *(const short8*)(As + aOff[i]);
#pragma unroll
        for (int i = 0; i < 4; ++i) b[i] = *(const short8*)(Bs + bOff[i]);
#pragma unroll
        for (int i = 0; i < 4; ++i)
#pragma unroll
            for (int j = 0; j < 4; ++j)
                acc[i][j] = __builtin_amdgcn_mfma_f32_16x16x32_bf16(a[i], b[j], acc[i][j], 0, 0, 0);
    }

#pragma unroll
    for (int mi = 0; mi < 4; ++mi) {
#pragma unroll
        for (int r = 0; r < 4; ++r) {
            const int rLoc = wr * 64 + mi * 16 + q * 4 + r;
            const int rLab = labR[rLoc];
            if (PASS == 1) {
                float vmin = 1e30f, vmax = -1e30f;
#pragma unroll
                for (int ni = 0; ni < 4; ++ni) {
                    float s = acc[mi][ni][r];
                    int cLab = labC[wc * 64 + ni * 16 + cIn];
                    if (rLab == cLab) {
                        if (s < 1.0f - EPSV) vmin = fminf(vmin, s);
                    } else {
                        vmax = fmaxf(vmax, s);
                    }
                }
#pragma unroll
                for (int off = 8; off; off >>= 1) {
                    vmin = fminf(vmin, __shfl_xor(vmin, off, 16));
                    vmax = fmaxf(vmax, __shfl_xor(vmax, off, 16));
                }
                if (cIn == 0) {
                    if (vmin < 1e30f) atomicMin(&minp_ord[rowBase + rLoc], f2ord(vmin));
                    if (vmax > -1e30f) atomicMax(&maxn_ord[rowBase + rLoc], f2ord(vmax));
                }
            } else {
                const float mp = mpS[rLoc] - MARGIN;
                const float mn = mnS[rLoc] + MARGIN;
                float ps = 0.f, ns = 0.f;
#pragma unroll
                for (int ni = 0; ni < 4; ++ni) {
                    float s = acc[mi][ni][r];
                    int cLab = labC[wc * 64 + ni * 16 + cIn];
                    if (rLab == cLab) {
                        if (s < 1.0f - EPSV && s < mn) ps += expf(-SCALE_POS * (s - THRESH));
                    } else {
                        if (s > mp) ns += expf(SCALE_NEG * (s - THRESH));
                    }
                }
#pragma unroll
                for (int off = 8; off; off >>= 1) {
                    ps += __shfl_xor(ps, off, 16);
                    ns += __shfl_xor(ns, off, 16);
                }
                if (cIn == 0) {
                    if (ps != 0.f) atomicAdd(&psum[rowBase + rLoc], ps);
                    if (ns != 0.f) atomicAdd(&nsum[rowBase + rLoc], ns);
                }
            }
        }
    }
}

// ---- final scalar reduction ----
__global__ void k_final(const float* __restrict__ psum, const float* __restrict__ nsum,
                        float* __restrict__ out, int B) {
    __shared__ float red[4];
    float acc = 0.f;
    for (int i = threadIdx.x; i < B; i += 256) {
        float p = psum[i], n = nsum[i];
        if (p > 0.f && n > 0.f)
            acc += log1pf(p) * (1.0f / SCALE_POS) + log1pf(n) * (1.0f / SCALE_NEG);
    }
#pragma unroll
    for (int off = 32; off; off >>= 1) acc += __shfl_down(acc, off, 64);
    if ((threadIdx.x & 63) == 0) red[threadIdx.x >> 6] = acc;
    __syncthreads();
    if (threadIdx.x == 0) out[0] = (red[0] + red[1] + red[2] + red[3]) / (float)B;
}

extern "C" void kernel_launch(void* const* d_in, const int* in_sizes, int n_in,
                              void* d_out, int out_size, void* d_ws, size_t ws_size,
                              hipStream_t stream) {
    const float* feats = (const float*)d_in[0];
    const int* labels = (const int*)d_in[1];
    const int B = in_sizes[1];            // 4096
    const int D = in_sizes[0] / B;        // 1024
    const int nb = B / 128;               // 32
    const int NT = nb * (nb + 1) / 2;     // 528

    char* ws = (char*)d_ws;
    unsigned short* fb16 = (unsigned short*)ws;
    size_t off = (size_t)B * D * sizeof(unsigned short);
    unsigned* minp = (unsigned*)(ws + off); off += (size_t)B * 4;
    unsigned* maxn = (unsigned*)(ws + off); off += (size_t)B * 4;
    float* psum = (float*)(ws + off); off += (size_t)B * 4;
    float* nsum = (float*)(ws + off); off += (size_t)B * 4;
    _Float16* simh = (_Float16*)(ws + ((off + 255) & ~(size_t)255));
    size_t need = ((off + 255) & ~(size_t)255) + (size_t)NT * 16384 * sizeof(_Float16);

    const int total4 = B * D / 4;
    k_init<<<(total4 + 255) / 256, 256, 0, stream>>>(feats, fb16, minp, maxn, psum, nsum, total4, B);

    if (ws_size >= need) {
        k_gemm_sym<<<NT, 256, 0, stream>>>(fb16, labels, minp, maxn, simh, D, nb);
        k_sum2<<<NT, 256, 0, stream>>>(simh, labels, minp, maxn, psum, nsum, nb);
    } else {
        dim3 grid(B / 128, B / 128);
        k_gemm<1><<<grid, 256, 0, stream>>>(fb16, labels, minp, maxn, psum, nsum, D);
        k_gemm<2><<<grid, 256, 0, stream>>>(fb16, labels, minp, maxn, psum, nsum, D);
    }

    k_final<<<1, 256, 0, stream>>>(psum, nsum, (float*)d_out, B);
}